// Round 9
// baseline (234.807 us; speedup 1.0000x reference)
//
#include <hip/hip_runtime.h>

typedef __attribute__((ext_vector_type(4))) float f32x4;
typedef __attribute__((ext_vector_type(16))) float f32x16;
typedef __attribute__((ext_vector_type(4))) unsigned short u16x4;
typedef __attribute__((ext_vector_type(8))) unsigned short u16x8;
typedef __attribute__((ext_vector_type(4))) unsigned int u32x4;
typedef __attribute__((ext_vector_type(8))) __bf16 bf16x8;

__device__ __forceinline__ unsigned short f2bf(float f) {
  unsigned int u = __builtin_bit_cast(unsigned int, f);
  u += 0x7fffu + ((u >> 16) & 1u);
  return (unsigned short)(u >> 16);
}

__device__ __forceinline__ bf16x8 ld_bf8(const unsigned short* p) {
  return __builtin_bit_cast(bf16x8, *(const u16x8*)p);
}

__device__ __forceinline__ f32x4 mfma16(bf16x8 a, bf16x8 b, f32x4 c) {
  return __builtin_amdgcn_mfma_f32_16x16x32_bf16(a, b, c, 0, 0, 0);
}

__device__ __forceinline__ f32x16 mfma32(bf16x8 a, bf16x8 b, f32x16 c) {
  return __builtin_amdgcn_mfma_f32_32x32x16_bf16(a, b, c, 0, 0, 0);
}

__device__ __forceinline__ unsigned int cvt_pk_bf16(float lo, float hi) {
  unsigned int r;
  asm("v_cvt_pk_bf16_f32 %0, %1, %2" : "=v"(r) : "v"(lo), "v"(hi));
  return r;
}

__device__ __forceinline__ void plane32_swap(unsigned int& a, unsigned int& b) {
  asm("v_permlane32_swap_b32 %0, %1" : "+v"(a), "+v"(b));
}

// ---------------- fp32 -> bf16 convert ----------------
__global__ void cvt_kernel(const float* __restrict__ in,
                           unsigned short* __restrict__ out, int n) {
  int i = (blockIdx.x * 256 + threadIdx.x) * 4;
  if (i >= n) return;
  f32x4 v = *(const f32x4*)(in + i);
  u16x4 r;
  r[0] = f2bf(v[0]); r[1] = f2bf(v[1]); r[2] = f2bf(v[2]); r[3] = f2bf(v[3]);
  *(u16x4*)(out + i) = r;
}

// ---------------- GEMM: C[m,n] = sum_k A[m,k]*W[n,k] + bias[n] ----------------
template <int EPI>
__global__ __launch_bounds__(256) void gemm_bt(const unsigned short* __restrict__ A,
                                               const unsigned short* __restrict__ Bw,
                                               const float* __restrict__ bias,
                                               void* __restrict__ Cout) {
  const int l = threadIdx.x & 63;
  const int w = threadIdx.x >> 6;
  const int g = l >> 4;
  const int lr = l & 15;
  const int m0 = blockIdx.y * 128 + (w >> 1) * 64;
  const int n0 = blockIdx.x * 128 + (w & 1) * 64;

  f32x4 acc[4][4];
#pragma unroll
  for (int i = 0; i < 4; i++)
#pragma unroll
    for (int j = 0; j < 4; j++) acc[i][j] = f32x4{0.f, 0.f, 0.f, 0.f};

  const unsigned short* pA = A + (size_t)(m0 + lr) * 512 + g * 8;
  const unsigned short* pB = Bw + (size_t)(n0 + lr) * 512 + g * 8;

  for (int k = 0; k < 512; k += 32) {
    bf16x8 af[4], bfr[4];
#pragma unroll
    for (int t = 0; t < 4; t++) af[t] = ld_bf8(pA + t * (16 * 512) + k);
#pragma unroll
    for (int t = 0; t < 4; t++) bfr[t] = ld_bf8(pB + t * (16 * 512) + k);
#pragma unroll
    for (int i = 0; i < 4; i++)
#pragma unroll
      for (int j = 0; j < 4; j++)
        acc[i][j] = mfma16(af[i], bfr[j], acc[i][j]);
  }

#pragma unroll
  for (int j = 0; j < 4; j++) {
    const int n = n0 + j * 16 + lr;
    const float bn = bias[n];
#pragma unroll
    for (int i = 0; i < 4; i++) {
#pragma unroll
      for (int r = 0; r < 4; r++) {
        const int m = m0 + i * 16 + g * 4 + r;
        const float v = acc[i][j][r] + bn;
        if (EPI == 0) {
          ((unsigned short*)Cout)[(size_t)m * 512 + n] = f2bf(v);
        } else if (EPI == 1) {
          const int bb = m >> 11, s = m & 2047;
          const int hh = n >> 6, d = n & 63;
          ((unsigned short*)Cout)[((size_t)((bb * 8 + hh) * 64 + d) << 11) + s] = f2bf(v);
        } else {
          ((float*)Cout)[(size_t)m * 512 + n] = v;
        }
      }
    }
  }
}

// ---------------- flash attention, intra-block split-KV (4 waves), KVBLK=32 ----------------
// Qp/Kp: [B*2048, 512] bf16 (head slice at h*64). Vt: [B,H,64,2048] bf16.
// Block = 4 waves, 32 q-rows TOTAL; wave w handles KV range [w*512,(w+1)*512) in 16
// tiles of 32. KVBLK=32 halves live registers vs r8 (target <=128 unified VGPR+AGPR
// -> 4 waves/SIMD). No K-prefetch pipeline: TLP replaces ILP at 4 waves/SIMD.
__global__ __launch_bounds__(256, 4) void attn_kernel(const unsigned short* __restrict__ Qp,
                                                      const unsigned short* __restrict__ Kp,
                                                      const unsigned short* __restrict__ Vt,
                                                      const float* __restrict__ rel_emb,
                                                      unsigned short* __restrict__ At) {
  __shared__ float bias_s[257];
  __shared__ float o_lds[4][32][64];
  __shared__ float ml_lds[4][2][32];
  const int bid = blockIdx.x;
  const int qb = bid & 63;
  const int h = (bid >> 6) & 7;
  const int b = bid >> 9;
  const int tid = threadIdx.x;
  for (int i = tid; i < 257; i += 256) bias_s[i] = rel_emb[i * 8 + h] * 1.44269504f;
  __syncthreads();
  const float bias_lo = bias_s[0], bias_hi = bias_s[256];

  const int lane = tid & 63, w = tid >> 6;
  const int hi = lane >> 5, q31 = lane & 31;
  const int q0w = qb * 32;        // block's 32 q-rows (shared by all waves)
  const int tq = q0w + q31;
  const int s_base = w << 9;      // this wave's KV quarter
  const float SCL = 0.125f * 1.44269504f;  // 1/sqrt(64) * log2(e)

  const unsigned short* qptr = Qp + (size_t)(b * 2048 + tq) * 512 + h * 64 + hi * 8;
  const bf16x8 qf0 = ld_bf8(qptr);
  const bf16x8 qf1 = ld_bf8(qptr + 16);
  const bf16x8 qf2 = ld_bf8(qptr + 32);
  const bf16x8 qf3 = ld_bf8(qptr + 48);

  const unsigned short* kbase = Kp + (size_t)(b * 2048) * 512 + h * 64 + hi * 8;
  const unsigned short* vb_lo = Vt + (((size_t)((b * 8 + h) * 64 + q31)) << 11) + hi * 8;
  const unsigned short* vb_hi = vb_lo + ((size_t)32 << 11);

  const f32x16 z16 = {0.f, 0.f, 0.f, 0.f, 0.f, 0.f, 0.f, 0.f,
                      0.f, 0.f, 0.f, 0.f, 0.f, 0.f, 0.f, 0.f};
  f32x16 o_lo = z16, o_hi = z16;
  float m_run = -1e30f, l_run = 0.f;

  for (int t = 0; t < 16; ++t) {
    const int s0 = s_base + t * 32;

    // ---- K frags + QK^T (swapped): sa[r] = P[kv row][q=q31] ----
    const unsigned short* krA = kbase + (size_t)(s0 + q31) * 512;
    f32x16 sa;
    {
      const bf16x8 k0 = ld_bf8(krA);
      const bf16x8 k1 = ld_bf8(krA + 16);
      const bf16x8 k2 = ld_bf8(krA + 32);
      const bf16x8 k3 = ld_bf8(krA + 48);
      sa = mfma32(k0, qf0, z16);
      sa = mfma32(k1, qf1, sa);
      sa = mfma32(k2, qf2, sa);
      sa = mfma32(k3, qf3, sa);
    }

    // ---- V frags (issue before softmax; latency hides under VALU) ----
    bf16x8 vl[2], vh[2];
#pragma unroll
    for (int ks = 0; ks < 2; ks++) {
      vl[ks] = ld_bf8(vb_lo + s0 + ks * 16);
      vh[ks] = ld_bf8(vb_hi + s0 + ks * 16);
    }

    // ---- bias + scale ----
    const int relmin = q0w - s0 - 31;
    const int relmax = q0w + 31 - s0;
    if (relmin >= 128 || relmax <= -128) {
      const float bc = (relmin >= 128) ? bias_hi : bias_lo;
#pragma unroll
      for (int r = 0; r < 16; r++) sa[r] = fmaf(sa[r], SCL, bc);
    } else {
#pragma unroll
      for (int r = 0; r < 16; r++) {
        const int rowA = (r & 3) + 8 * (r >> 2) + 4 * hi;
        const int rA = tq - s0 - rowA;
        const int iA = (rA < -128 ? -128 : (rA > 128 ? 128 : rA)) + 128;
        sa[r] = fmaf(sa[r], SCL, bias_s[iA]);
      }
    }

    // ---- row max ----
    const float t0 = fmaxf(fmaxf(sa[0], sa[1]), sa[2]);
    const float t1 = fmaxf(fmaxf(sa[3], sa[4]), sa[5]);
    const float t2 = fmaxf(fmaxf(sa[6], sa[7]), sa[8]);
    const float t3 = fmaxf(fmaxf(sa[9], sa[10]), sa[11]);
    const float t4 = fmaxf(fmaxf(sa[12], sa[13]), sa[14]);
    float mx = fmaxf(fmaxf(fmaxf(t0, t1), fmaxf(t2, t3)), fmaxf(t4, sa[15]));
    mx = fmaxf(mx, __shfl_xor(mx, 32, 64));

    // ---- defer-max rescale ----
    if (!__all(mx <= m_run + 8.f)) {
      const float m_new = fmaxf(m_run, mx);
      const float rsq = exp2f(m_run - m_new);
      l_run *= rsq;
      m_run = m_new;
#pragma unroll
      for (int r2 = 0; r2 < 16; r2++) {
        const int ro = (r2 & 3) + 8 * (r2 >> 2) + 4 * hi;
        const float rr = __shfl(rsq, ro, 64);
        o_lo[r2] *= rr;
        o_hi[r2] *= rr;
      }
    }

    // ---- exp2 + sum ----
#pragma unroll
    for (int r = 0; r < 16; r++) sa[r] = exp2f(sa[r] - m_run);
    float s4[4];
#pragma unroll
    for (int i = 0; i < 4; i++)
      s4[i] = (sa[i] + sa[i + 4]) + (sa[i + 8] + sa[i + 12]);
    float ps = (s4[0] + s4[1]) + (s4[2] + s4[3]);
    ps += __shfl_xor(ps, 32, 64);
    l_run += ps;

    // ---- P -> PV A-frags (kv 0..15 -> pa0, kv 16..31 -> pa1) ----
    bf16x8 pa[2];
#pragma unroll
    for (int ks = 0; ks < 2; ks++) {
      const int c8 = ks * 8;
      unsigned int a0 = cvt_pk_bf16(sa[c8 + 0], sa[c8 + 1]);
      unsigned int b0 = cvt_pk_bf16(sa[c8 + 4], sa[c8 + 5]);
      unsigned int a1 = cvt_pk_bf16(sa[c8 + 2], sa[c8 + 3]);
      unsigned int b1 = cvt_pk_bf16(sa[c8 + 6], sa[c8 + 7]);
      plane32_swap(a0, b0);
      plane32_swap(a1, b1);
      pa[ks] = __builtin_bit_cast(bf16x8, u32x4{a0, a1, b0, b1});
    }

    // ---- PV ----
    o_lo = mfma32(pa[0], vl[0], o_lo);
    o_hi = mfma32(pa[0], vh[0], o_hi);
    o_lo = mfma32(pa[1], vl[1], o_lo);
    o_hi = mfma32(pa[1], vh[1], o_hi);
  }

  // ---- write per-wave partials to LDS ----
#pragma unroll
  for (int r2 = 0; r2 < 16; r2++) {
    const int ro = (r2 & 3) + 8 * (r2 >> 2) + 4 * hi;
    o_lds[w][ro][q31] = o_lo[r2];
    o_lds[w][ro][32 + q31] = o_hi[r2];
  }
  if (hi == 0) {
    ml_lds[w][0][q31] = m_run;
    ml_lds[w][1][q31] = l_run;
  }
  __syncthreads();

  // ---- 4-way LSE combine -> bf16 At; thread = (col, 8 rows) ----
  const int col = tid & 63;
  const int r0 = (tid >> 6) * 8;
  for (int rr = 0; rr < 8; ++rr) {
    const int row = r0 + rr;
    const float m0 = ml_lds[0][0][row], m1 = ml_lds[1][0][row];
    const float m2 = ml_lds[2][0][row], m3 = ml_lds[3][0][row];
    const float mc = fmaxf(fmaxf(m0, m1), fmaxf(m2, m3));
    const float w0 = exp2f(m0 - mc), w1 = exp2f(m1 - mc);
    const float w2 = exp2f(m2 - mc), w3 = exp2f(m3 - mc);
    const float lc = fmaf(ml_lds[0][1][row], w0,
                     fmaf(ml_lds[1][1][row], w1,
                     fmaf(ml_lds[2][1][row], w2, ml_lds[3][1][row] * w3)));
    const float ov = fmaf(o_lds[0][row][col], w0,
                     fmaf(o_lds[1][row][col], w1,
                     fmaf(o_lds[2][row][col], w2, o_lds[3][row][col] * w3)));
    At[(size_t)(b * 2048 + q0w + row) * 512 + h * 64 + col] = f2bf(ov / lc);
  }
}

// ---------------- host ----------------
extern "C" void kernel_launch(void* const* d_in, const int* in_sizes, int n_in,
                              void* d_out, int out_size, void* d_ws, size_t ws_size,
                              hipStream_t stream) {
  const float* query = (const float*)d_in[0];
  const float* key   = (const float*)d_in[1];
  const float* value = (const float*)d_in[2];
  const float* Wq = (const float*)d_in[3];
  const float* bq = (const float*)d_in[4];
  const float* Wk = (const float*)d_in[5];
  const float* bk = (const float*)d_in[6];
  const float* Wv = (const float*)d_in[7];
  const float* bv = (const float*)d_in[8];
  const float* Wo = (const float*)d_in[9];
  const float* bo = (const float*)d_in[10];
  const float* rel = (const float*)d_in[11];

  char* ws = (char*)d_ws;
  const size_t SZX = (size_t)4 * 2048 * 512;
  const size_t SZW = (size_t)512 * 512;
  unsigned short* xq = (unsigned short*)ws;
  unsigned short* xk = xq + SZX;
  unsigned short* xv = xk + SZX;
  unsigned short* wq = xv + SZX;
  unsigned short* wk = wq + SZW;
  unsigned short* wv = wk + SZW;
  unsigned short* wo = wv + SZW;
  unsigned short* Qp = wo + SZW;
  unsigned short* Kp = Qp + SZX;
  unsigned short* Vt = Kp + SZX;
  unsigned short* At = Vt + SZX;

  auto cvt = [&](const float* s, unsigned short* dst, int n) {
    cvt_kernel<<<dim3((n + 1023) / 1024), dim3(256), 0, stream>>>(s, dst, n);
  };
  cvt(query, xq, (int)SZX);
  cvt(key, xk, (int)SZX);
  cvt(value, xv, (int)SZX);
  cvt(Wq, wq, (int)SZW);
  cvt(Wk, wk, (int)SZW);
  cvt(Wv, wv, (int)SZW);
  cvt(Wo, wo, (int)SZW);

  dim3 gg(4, 64), blk(256);
  gemm_bt<0><<<gg, blk, 0, stream>>>(xq, wq, bq, (void*)Qp);
  gemm_bt<0><<<gg, blk, 0, stream>>>(xk, wk, bk, (void*)Kp);
  gemm_bt<1><<<gg, blk, 0, stream>>>(xv, wv, bv, (void*)Vt);

  attn_kernel<<<dim3(2048), blk, 0, stream>>>(Qp, Kp, Vt, rel, At);

  gemm_bt<2><<<gg, blk, 0, stream>>>(At, wo, bo, d_out);
}

// Round 10
// 177.548 us; speedup vs baseline: 1.3225x; 1.3225x over previous
//
#include <hip/hip_runtime.h>

typedef __attribute__((ext_vector_type(4))) float f32x4;
typedef __attribute__((ext_vector_type(16))) float f32x16;
typedef __attribute__((ext_vector_type(4))) unsigned short u16x4;
typedef __attribute__((ext_vector_type(8))) unsigned short u16x8;
typedef __attribute__((ext_vector_type(4))) unsigned int u32x4;
typedef __attribute__((ext_vector_type(8))) __bf16 bf16x8;

__device__ __forceinline__ unsigned short f2bf(float f) {
  unsigned int u = __builtin_bit_cast(unsigned int, f);
  u += 0x7fffu + ((u >> 16) & 1u);
  return (unsigned short)(u >> 16);
}

__device__ __forceinline__ bf16x8 ld_bf8(const unsigned short* p) {
  return __builtin_bit_cast(bf16x8, *(const u16x8*)p);
}

__device__ __forceinline__ f32x4 mfma16(bf16x8 a, bf16x8 b, f32x4 c) {
  return __builtin_amdgcn_mfma_f32_16x16x32_bf16(a, b, c, 0, 0, 0);
}

__device__ __forceinline__ f32x16 mfma32(bf16x8 a, bf16x8 b, f32x16 c) {
  return __builtin_amdgcn_mfma_f32_32x32x16_bf16(a, b, c, 0, 0, 0);
}

__device__ __forceinline__ unsigned int cvt_pk_bf16(float lo, float hi) {
  unsigned int r;
  asm("v_cvt_pk_bf16_f32 %0, %1, %2" : "=v"(r) : "v"(lo), "v"(hi));
  return r;
}

__device__ __forceinline__ void plane32_swap(unsigned int& a, unsigned int& b) {
  asm("v_permlane32_swap_b32 %0, %1" : "+v"(a), "+v"(b));
}

// async global->LDS, 16B per lane; LDS dest = uniform base + lane*16 (HW rule)
__device__ __forceinline__ void gload16(const void* g, void* l) {
  __builtin_amdgcn_global_load_lds(
      (const __attribute__((address_space(1))) unsigned int*)g,
      (__attribute__((address_space(3))) unsigned int*)l, 16, 0, 0);
}

// ---------------- fp32 -> bf16 convert ----------------
__global__ void cvt_kernel(const float* __restrict__ in,
                           unsigned short* __restrict__ out, int n) {
  int i = (blockIdx.x * 256 + threadIdx.x) * 4;
  if (i >= n) return;
  f32x4 v = *(const f32x4*)(in + i);
  u16x4 r;
  r[0] = f2bf(v[0]); r[1] = f2bf(v[1]); r[2] = f2bf(v[2]); r[3] = f2bf(v[3]);
  *(u16x4*)(out + i) = r;
}

// ---------------- GEMM: C[m,n] = sum_k A[m,k]*W[n,k] + bias[n] ----------------
template <int EPI>
__global__ __launch_bounds__(256) void gemm_bt(const unsigned short* __restrict__ A,
                                               const unsigned short* __restrict__ Bw,
                                               const float* __restrict__ bias,
                                               void* __restrict__ Cout) {
  const int l = threadIdx.x & 63;
  const int w = threadIdx.x >> 6;
  const int g = l >> 4;
  const int lr = l & 15;
  const int m0 = blockIdx.y * 128 + (w >> 1) * 64;
  const int n0 = blockIdx.x * 128 + (w & 1) * 64;

  f32x4 acc[4][4];
#pragma unroll
  for (int i = 0; i < 4; i++)
#pragma unroll
    for (int j = 0; j < 4; j++) acc[i][j] = f32x4{0.f, 0.f, 0.f, 0.f};

  const unsigned short* pA = A + (size_t)(m0 + lr) * 512 + g * 8;
  const unsigned short* pB = Bw + (size_t)(n0 + lr) * 512 + g * 8;

  for (int k = 0; k < 512; k += 32) {
    bf16x8 af[4], bfr[4];
#pragma unroll
    for (int t = 0; t < 4; t++) af[t] = ld_bf8(pA + t * (16 * 512) + k);
#pragma unroll
    for (int t = 0; t < 4; t++) bfr[t] = ld_bf8(pB + t * (16 * 512) + k);
#pragma unroll
    for (int i = 0; i < 4; i++)
#pragma unroll
      for (int j = 0; j < 4; j++)
        acc[i][j] = mfma16(af[i], bfr[j], acc[i][j]);
  }

#pragma unroll
  for (int j = 0; j < 4; j++) {
    const int n = n0 + j * 16 + lr;
    const float bn = bias[n];
#pragma unroll
    for (int i = 0; i < 4; i++) {
#pragma unroll
      for (int r = 0; r < 4; r++) {
        const int m = m0 + i * 16 + g * 4 + r;
        const float v = acc[i][j][r] + bn;
        if (EPI == 0) {
          ((unsigned short*)Cout)[(size_t)m * 512 + n] = f2bf(v);
        } else if (EPI == 1) {
          const int bb = m >> 11, s = m & 2047;
          const int hh = n >> 6, d = n & 63;
          ((unsigned short*)Cout)[((size_t)((bb * 8 + hh) * 64 + d) << 11) + s] = f2bf(v);
        } else {
          ((float*)Cout)[(size_t)m * 512 + n] = v;
        }
      }
    }
  }
}

// ---------------- flash attention: LDS-staged K/V, 4 waves x 32 q-rows ----------------
// Qp/Kp: [B*2048, 512] bf16 (head slice at h*64). Vt: [B,H,64,2048] bf16.
// Block = 128 q-rows (wave w owns rows [w*32,(w+1)*32)); KV tiles of 64 staged in LDS
// (double-buffered). Swizzle: linear gload_lds dest + inverse-swizzled global src +
// XOR-swizzled ds_read (chunk ^= row&7) per rule #21 / T2.
__global__ __launch_bounds__(256, 2) void attn_kernel(const unsigned short* __restrict__ Qp,
                                                      const unsigned short* __restrict__ Kp,
                                                      const unsigned short* __restrict__ Vt,
                                                      const float* __restrict__ rel_emb,
                                                      unsigned short* __restrict__ At) {
  __shared__ float bias_s[257];
  __shared__ unsigned short K_lds[2][4096];  // [64 kv][64 d] swizzled, 8 KB each
  __shared__ unsigned short V_lds[2][4096];  // [64 d][64 s] swizzled
  const int bid = blockIdx.x;
  const int qb = bid & 15;
  const int h = (bid >> 4) & 7;
  const int b = bid >> 7;
  const int tid = threadIdx.x;
  const int lane = tid & 63, w = tid >> 6;
  const int hi = lane >> 5, q31 = lane & 31;
  const int q0w = qb * 128 + w * 32;
  const int tq = q0w + q31;
  const float SCL = 0.125f * 1.44269504f;  // 1/sqrt(64) * log2(e)

  const char* kstage = (const char*)Kp + ((size_t)b * 2048 * 512 + h * 64) * 2;
  const char* vstage = (const char*)Vt + ((size_t)(b * 8 + h) * 64 * 2048) * 2;

  // stage one 64-wide KV tile into buffer bufi: waves 0,1 -> K, waves 2,3 -> V.
  // dest linear (i*1024 + lane*16); src chunk pre-swizzled (ch ^= row&7).
  auto stage = [&](int bufi, int s0n) {
#pragma unroll
    for (int ii = 0; ii < 4; ii++) {
      const int ins = (w & 1) * 4 + ii;           // instruction 0..7
      const int r = ins * 8 + (lane >> 3);        // tile row 0..63
      const int ch = (lane & 7) ^ (r & 7);        // inverse-swizzled 16B chunk
      if (w < 2) {
        gload16(kstage + (size_t)(s0n + r) * 1024 + ch * 16,
                (char*)&K_lds[bufi][0] + ins * 1024);
      } else {
        gload16(vstage + (size_t)r * 4096 + (size_t)s0n * 2 + ch * 16,
                (char*)&V_lds[bufi][0] + ins * 1024);
      }
    }
  };

  for (int i = tid; i < 257; i += 256) bias_s[i] = rel_emb[i * 8 + h] * 1.44269504f;
  stage(0, 0);
  __syncthreads();
  const float bias_lo = bias_s[0], bias_hi = bias_s[256];

  const unsigned short* qptr = Qp + (size_t)(b * 2048 + tq) * 512 + h * 64 + hi * 8;
  const bf16x8 qf0 = ld_bf8(qptr);
  const bf16x8 qf1 = ld_bf8(qptr + 16);
  const bf16x8 qf2 = ld_bf8(qptr + 32);
  const bf16x8 qf3 = ld_bf8(qptr + 48);

  const f32x16 z16 = {0.f, 0.f, 0.f, 0.f, 0.f, 0.f, 0.f, 0.f,
                      0.f, 0.f, 0.f, 0.f, 0.f, 0.f, 0.f, 0.f};
  f32x16 o_lo = z16, o_hi = z16;
  float m_run = -1e30f, l_run = 0.f;
  int buf = 0;

  for (int t = 0; t < 32; ++t) {
    const int s0 = t * 64;
    if (t != 31) stage(buf ^ 1, s0 + 64);

    // ---- K frags from LDS (swizzled read) + QK^T (swapped) ----
    const unsigned short* kb = &K_lds[buf][0];
    const int rswz = q31 & 7;  // == (32+q31)&7
    f32x16 sa, sb;
    sa = mfma32(ld_bf8(kb + q31 * 64 + (((0 + hi) ^ rswz) << 3)), qf0, z16);
    sb = mfma32(ld_bf8(kb + (32 + q31) * 64 + (((0 + hi) ^ rswz) << 3)), qf0, z16);
    sa = mfma32(ld_bf8(kb + q31 * 64 + (((2 + hi) ^ rswz) << 3)), qf1, sa);
    sb = mfma32(ld_bf8(kb + (32 + q31) * 64 + (((2 + hi) ^ rswz) << 3)), qf1, sb);
    sa = mfma32(ld_bf8(kb + q31 * 64 + (((4 + hi) ^ rswz) << 3)), qf2, sa);
    sb = mfma32(ld_bf8(kb + (32 + q31) * 64 + (((4 + hi) ^ rswz) << 3)), qf2, sb);
    sa = mfma32(ld_bf8(kb + q31 * 64 + (((6 + hi) ^ rswz) << 3)), qf3, sa);
    sb = mfma32(ld_bf8(kb + (32 + q31) * 64 + (((6 + hi) ^ rswz) << 3)), qf3, sb);

    // ---- V frags from LDS ----
    const unsigned short* vb = &V_lds[buf][0];
    bf16x8 vl[4], vh[4];
#pragma unroll
    for (int ks = 0; ks < 4; ks++) {
      vl[ks] = ld_bf8(vb + q31 * 64 + (((ks * 2 + hi) ^ rswz) << 3));
      vh[ks] = ld_bf8(vb + (32 + q31) * 64 + (((ks * 2 + hi) ^ rswz) << 3));
    }

    // ---- bias + scale ----
    const int relmin = q0w - s0 - 63;
    const int relmax = q0w + 31 - s0;
    if (relmin >= 128 || relmax <= -128) {
      const float bc = (relmin >= 128) ? bias_hi : bias_lo;
#pragma unroll
      for (int r = 0; r < 16; r++) {
        sa[r] = fmaf(sa[r], SCL, bc);
        sb[r] = fmaf(sb[r], SCL, bc);
      }
    } else {
#pragma unroll
      for (int r = 0; r < 16; r++) {
        const int rowA = (r & 3) + 8 * (r >> 2) + 4 * hi;
        const int rA = tq - s0 - rowA;
        const int rB = rA - 32;
        const int iA = (rA < -128 ? -128 : (rA > 128 ? 128 : rA)) + 128;
        const int iB = (rB < -128 ? -128 : (rB > 128 ? 128 : rB)) + 128;
        sa[r] = fmaf(sa[r], SCL, bias_s[iA]);
        sb[r] = fmaf(sb[r], SCL, bias_s[iB]);
      }
    }

    // ---- row max ----
    const float t0 = fmaxf(fmaxf(sa[0], sa[1]), sa[2]);
    const float t1 = fmaxf(fmaxf(sa[3], sa[4]), sa[5]);
    const float t2 = fmaxf(fmaxf(sa[6], sa[7]), sa[8]);
    const float t3 = fmaxf(fmaxf(sa[9], sa[10]), sa[11]);
    const float t4 = fmaxf(fmaxf(sa[12], sa[13]), sa[14]);
    const float t5 = fmaxf(fmaxf(sa[15], sb[0]), sb[1]);
    const float t6 = fmaxf(fmaxf(sb[2], sb[3]), sb[4]);
    const float t7 = fmaxf(fmaxf(sb[5], sb[6]), sb[7]);
    const float t8 = fmaxf(fmaxf(sb[8], sb[9]), sb[10]);
    const float t9 = fmaxf(fmaxf(sb[11], sb[12]), sb[13]);
    const float ta = fmaxf(sb[14], sb[15]);
    const float u0 = fmaxf(fmaxf(t0, t1), t2);
    const float u1 = fmaxf(fmaxf(t3, t4), t5);
    const float u2 = fmaxf(fmaxf(t6, t7), t8);
    float mx = fmaxf(fmaxf(fmaxf(u0, u1), u2), fmaxf(t9, ta));
    mx = fmaxf(mx, __shfl_xor(mx, 32, 64));

    // ---- defer-max rescale ----
    if (!__all(mx <= m_run + 8.f)) {
      const float m_new = fmaxf(m_run, mx);
      const float rsq = exp2f(m_run - m_new);
      l_run *= rsq;
      m_run = m_new;
#pragma unroll
      for (int r2 = 0; r2 < 16; r2++) {
        const int ro = (r2 & 3) + 8 * (r2 >> 2) + 4 * hi;
        const float rr = __shfl(rsq, ro, 64);
        o_lo[r2] *= rr;
        o_hi[r2] *= rr;
      }
    }

    // ---- exp2 + sum ----
#pragma unroll
    for (int r = 0; r < 16; r++) {
      sa[r] = exp2f(sa[r] - m_run);
      sb[r] = exp2f(sb[r] - m_run);
    }
    float s8[8];
#pragma unroll
    for (int i = 0; i < 8; i++)
      s8[i] = (sa[i] + sa[i + 8]) + (sb[i] + sb[i + 8]);
    float ps = ((s8[0] + s8[1]) + (s8[2] + s8[3])) + ((s8[4] + s8[5]) + (s8[6] + s8[7]));
    ps += __shfl_xor(ps, 32, 64);
    l_run += ps;

    // ---- P -> PV A-frags via cvt_pk + permlane32_swap ----
    bf16x8 pa[4];
#pragma unroll
    for (int ks = 0; ks < 4; ks++) {
      const int c8 = (ks & 1) * 8;
      const f32x16& src = (ks < 2) ? sa : sb;
      unsigned int a0 = cvt_pk_bf16(src[c8 + 0], src[c8 + 1]);
      unsigned int b0 = cvt_pk_bf16(src[c8 + 4], src[c8 + 5]);
      unsigned int a1 = cvt_pk_bf16(src[c8 + 2], src[c8 + 3]);
      unsigned int b1 = cvt_pk_bf16(src[c8 + 6], src[c8 + 7]);
      plane32_swap(a0, b0);
      plane32_swap(a1, b1);
      pa[ks] = __builtin_bit_cast(bf16x8, u32x4{a0, a1, b0, b1});
    }

    // ---- PV ----
#pragma unroll
    for (int ks = 0; ks < 4; ks++) {
      o_lo = mfma32(pa[ks], vl[ks], o_lo);
      o_hi = mfma32(pa[ks], vh[ks], o_hi);
    }

    __syncthreads();  // stage(t+1) drained + all waves done with buf
    buf ^= 1;
  }

  // ---- normalize + write this wave's 32 q-rows ----
  const float inv = 1.f / l_run;
#pragma unroll
  for (int r2 = 0; r2 < 16; r2++) {
    const int ro = (r2 & 3) + 8 * (r2 >> 2) + 4 * hi;
    const float rr = __shfl(inv, ro, 64);
    unsigned short* op = At + (size_t)(b * 2048 + q0w + ro) * 512 + h * 64;
    op[q31] = f2bf(o_lo[r2] * rr);
    op[32 + q31] = f2bf(o_hi[r2] * rr);
  }
}

// ---------------- host ----------------
extern "C" void kernel_launch(void* const* d_in, const int* in_sizes, int n_in,
                              void* d_out, int out_size, void* d_ws, size_t ws_size,
                              hipStream_t stream) {
  const float* query = (const float*)d_in[0];
  const float* key   = (const float*)d_in[1];
  const float* value = (const float*)d_in[2];
  const float* Wq = (const float*)d_in[3];
  const float* bq = (const float*)d_in[4];
  const float* Wk = (const float*)d_in[5];
  const float* bk = (const float*)d_in[6];
  const float* Wv = (const float*)d_in[7];
  const float* bv = (const float*)d_in[8];
  const float* Wo = (const float*)d_in[9];
  const float* bo = (const float*)d_in[10];
  const float* rel = (const float*)d_in[11];

  char* ws = (char*)d_ws;
  const size_t SZX = (size_t)4 * 2048 * 512;
  const size_t SZW = (size_t)512 * 512;
  unsigned short* xq = (unsigned short*)ws;
  unsigned short* xk = xq + SZX;
  unsigned short* xv = xk + SZX;
  unsigned short* wq = xv + SZX;
  unsigned short* wk = wq + SZW;
  unsigned short* wv = wk + SZW;
  unsigned short* wo = wv + SZW;
  unsigned short* Qp = wo + SZW;
  unsigned short* Kp = Qp + SZX;
  unsigned short* Vt = Kp + SZX;
  unsigned short* At = Vt + SZX;

  auto cvt = [&](const float* s, unsigned short* dst, int n) {
    cvt_kernel<<<dim3((n + 1023) / 1024), dim3(256), 0, stream>>>(s, dst, n);
  };
  cvt(query, xq, (int)SZX);
  cvt(key, xk, (int)SZX);
  cvt(value, xv, (int)SZX);
  cvt(Wq, wq, (int)SZW);
  cvt(Wk, wk, (int)SZW);
  cvt(Wv, wv, (int)SZW);
  cvt(Wo, wo, (int)SZW);

  dim3 gg(4, 64), blk(256);
  gemm_bt<0><<<gg, blk, 0, stream>>>(xq, wq, bq, (void*)Qp);
  gemm_bt<0><<<gg, blk, 0, stream>>>(xk, wk, bk, (void*)Kp);
  gemm_bt<1><<<gg, blk, 0, stream>>>(xv, wv, bv, (void*)Vt);

  attn_kernel<<<dim3(512), blk, 0, stream>>>(Qp, Kp, Vt, rel, At);

  gemm_bt<2><<<gg, blk, 0, stream>>>(At, wo, bo, d_out);
}

// Round 11
// 138.487 us; speedup vs baseline: 1.6955x; 1.2821x over previous
//
#include <hip/hip_runtime.h>

typedef __attribute__((ext_vector_type(4))) float f32x4;
typedef __attribute__((ext_vector_type(16))) float f32x16;
typedef __attribute__((ext_vector_type(4))) unsigned short u16x4;
typedef __attribute__((ext_vector_type(8))) unsigned short u16x8;
typedef __attribute__((ext_vector_type(4))) unsigned int u32x4;
typedef __attribute__((ext_vector_type(8))) __bf16 bf16x8;

__device__ __forceinline__ unsigned short f2bf(float f) {
  unsigned int u = __builtin_bit_cast(unsigned int, f);
  u += 0x7fffu + ((u >> 16) & 1u);
  return (unsigned short)(u >> 16);
}

__device__ __forceinline__ bf16x8 ld_bf8(const unsigned short* p) {
  return __builtin_bit_cast(bf16x8, *(const u16x8*)p);
}

__device__ __forceinline__ f32x4 mfma16(bf16x8 a, bf16x8 b, f32x4 c) {
  return __builtin_amdgcn_mfma_f32_16x16x32_bf16(a, b, c, 0, 0, 0);
}

__device__ __forceinline__ f32x16 mfma32(bf16x8 a, bf16x8 b, f32x16 c) {
  return __builtin_amdgcn_mfma_f32_32x32x16_bf16(a, b, c, 0, 0, 0);
}

__device__ __forceinline__ unsigned int cvt_pk_bf16(float lo, float hi) {
  unsigned int r;
  asm("v_cvt_pk_bf16_f32 %0, %1, %2" : "=v"(r) : "v"(lo), "v"(hi));
  return r;
}

__device__ __forceinline__ void plane32_swap(unsigned int& a, unsigned int& b) {
  asm("v_permlane32_swap_b32 %0, %1" : "+v"(a), "+v"(b));
}

// async global->LDS, 16B per lane; LDS dest = WAVE-UNIFORM base, HW adds lane*16
__device__ __forceinline__ void gload16(const void* g, void* l) {
  __builtin_amdgcn_global_load_lds(
      (const __attribute__((address_space(1))) unsigned int*)g,
      (__attribute__((address_space(3))) unsigned int*)l, 16, 0, 0);
}

// ---------------- fused fp32 -> bf16 convert (all 7 tensors, one launch) ----------------
// out = ws base; segments contiguous: xq,xk,xv (4096 blocks each), wq,wk,wv,wo (256 each).
__global__ __launch_bounds__(256) void cvt_all(const float* __restrict__ q_,
                                               const float* __restrict__ k_,
                                               const float* __restrict__ v_,
                                               const float* __restrict__ wq_,
                                               const float* __restrict__ wk_,
                                               const float* __restrict__ wv_,
                                               const float* __restrict__ wo_,
                                               unsigned short* __restrict__ out) {
  const int bq = blockIdx.x;
  const float* src;
  size_t segbase, li;
  if (bq < 12288) {
    const int s = bq >> 12;
    src = (s == 0) ? q_ : (s == 1) ? k_ : v_;
    li = (size_t)(bq & 4095) * 256 + threadIdx.x;
    segbase = (size_t)s * 4194304;
  } else {
    const int s = (bq - 12288) >> 8;
    src = (s == 0) ? wq_ : (s == 1) ? wk_ : (s == 2) ? wv_ : wo_;
    li = (size_t)((bq - 12288) & 255) * 256 + threadIdx.x;
    segbase = 12582912 + (size_t)s * 262144;
  }
  const f32x4 v = *(const f32x4*)(src + li * 4);
  u16x4 r;
  r[0] = f2bf(v[0]); r[1] = f2bf(v[1]); r[2] = f2bf(v[2]); r[3] = f2bf(v[3]);
  *(u16x4*)(out + segbase + li * 4) = r;
}

// ---------------- GEMM: C[m,n] = sum_k A[m,k]*W[n,k] + bias[n] ----------------
// m97 structure: 128x128 tile, BK=32, double-buffered LDS via global_load_lds w=16.
template <int EPI>
__global__ __launch_bounds__(256) void gemm_bt(const unsigned short* __restrict__ A,
                                               const unsigned short* __restrict__ Bw,
                                               const float* __restrict__ bias,
                                               void* __restrict__ Cout) {
  __shared__ unsigned short Asb[2][4096];  // [128 rows][32 k] bf16, 8 KB
  __shared__ unsigned short Bsb[2][4096];
  const int tid = threadIdx.x;
  const int l = tid & 63;
  const int w = tid >> 6;
  const int g = l >> 4;
  const int lr = l & 15;
  const int mB = blockIdx.y * 128;
  const int nB = blockIdx.x * 128;
  const int m0 = (w >> 1) * 64;
  const int n0 = (w & 1) * 64;
  const int ubase = tid & ~63;  // wave-uniform chunk base

  auto stage = [&](int bufi, int kk) {
#pragma unroll
    for (int i = 0; i < 2; i++) {
      const int idx = i * 256 + tid;   // per-lane chunk id (src addressing)
      const int ub = i * 256 + ubase;  // wave-uniform dest chunk base
      const int r = idx >> 2, c = idx & 3;
      gload16((const char*)A + ((size_t)(mB + r) * 512 + kk + c * 8) * 2,
              (char*)&Asb[bufi][0] + ub * 16);
      gload16((const char*)Bw + ((size_t)(nB + r) * 512 + kk + c * 8) * 2,
              (char*)&Bsb[bufi][0] + ub * 16);
    }
  };

  f32x4 acc[4][4];
#pragma unroll
  for (int i = 0; i < 4; i++)
#pragma unroll
    for (int j = 0; j < 4; j++) acc[i][j] = f32x4{0.f, 0.f, 0.f, 0.f};

  stage(0, 0);
  __syncthreads();
  int buf = 0;

  for (int ks = 0; ks < 16; ++ks) {
    if (ks < 15) stage(buf ^ 1, (ks + 1) * 32);
    bf16x8 af[4], bfr[4];
#pragma unroll
    for (int t = 0; t < 4; t++) {
      af[t] = ld_bf8(&Asb[buf][(m0 + t * 16 + lr) * 32 + g * 8]);
      bfr[t] = ld_bf8(&Bsb[buf][(n0 + t * 16 + lr) * 32 + g * 8]);
    }
#pragma unroll
    for (int i = 0; i < 4; i++)
#pragma unroll
      for (int j = 0; j < 4; j++)
        acc[i][j] = mfma16(af[i], bfr[j], acc[i][j]);
    __syncthreads();
    buf ^= 1;
  }

#pragma unroll
  for (int j = 0; j < 4; j++) {
    const int n = nB + n0 + j * 16 + lr;
    const float bn = bias[n];
#pragma unroll
    for (int i = 0; i < 4; i++) {
#pragma unroll
      for (int r = 0; r < 4; r++) {
        const int m = mB + m0 + i * 16 + g * 4 + r;
        const float v = acc[i][j][r] + bn;
        if (EPI == 0) {
          ((unsigned short*)Cout)[(size_t)m * 512 + n] = f2bf(v);
        } else if (EPI == 1) {
          const int bb = m >> 11, s = m & 2047;
          const int hh = n >> 6, d = n & 63;
          ((unsigned short*)Cout)[((size_t)((bb * 8 + hh) * 64 + d) << 11) + s] = f2bf(v);
        } else {
          ((float*)Cout)[(size_t)m * 512 + n] = v;
        }
      }
    }
  }
}

// ---------------- flash attention: LDS-staged K/V, 4 waves x 32 q-rows ----------------
// (unchanged from round 10 — verified, 79 us)
__global__ __launch_bounds__(256, 2) void attn_kernel(const unsigned short* __restrict__ Qp,
                                                      const unsigned short* __restrict__ Kp,
                                                      const unsigned short* __restrict__ Vt,
                                                      const float* __restrict__ rel_emb,
                                                      unsigned short* __restrict__ At) {
  __shared__ float bias_s[257];
  __shared__ unsigned short K_lds[2][4096];  // [64 kv][64 d] swizzled, 8 KB each
  __shared__ unsigned short V_lds[2][4096];  // [64 d][64 s] swizzled
  const int bid = blockIdx.x;
  const int qb = bid & 15;
  const int h = (bid >> 4) & 7;
  const int b = bid >> 7;
  const int tid = threadIdx.x;
  const int lane = tid & 63, w = tid >> 6;
  const int hi = lane >> 5, q31 = lane & 31;
  const int q0w = qb * 128 + w * 32;
  const int tq = q0w + q31;
  const float SCL = 0.125f * 1.44269504f;  // 1/sqrt(64) * log2(e)

  const char* kstage = (const char*)Kp + ((size_t)b * 2048 * 512 + h * 64) * 2;
  const char* vstage = (const char*)Vt + ((size_t)(b * 8 + h) * 64 * 2048) * 2;

  auto stage = [&](int bufi, int s0n) {
#pragma unroll
    for (int ii = 0; ii < 4; ii++) {
      const int ins = (w & 1) * 4 + ii;           // instruction 0..7
      const int r = ins * 8 + (lane >> 3);        // tile row 0..63
      const int ch = (lane & 7) ^ (r & 7);        // inverse-swizzled 16B chunk
      if (w < 2) {
        gload16(kstage + (size_t)(s0n + r) * 1024 + ch * 16,
                (char*)&K_lds[bufi][0] + ins * 1024);
      } else {
        gload16(vstage + (size_t)r * 4096 + (size_t)s0n * 2 + ch * 16,
                (char*)&V_lds[bufi][0] + ins * 1024);
      }
    }
  };

  for (int i = tid; i < 257; i += 256) bias_s[i] = rel_emb[i * 8 + h] * 1.44269504f;
  stage(0, 0);
  __syncthreads();
  const float bias_lo = bias_s[0], bias_hi = bias_s[256];

  const unsigned short* qptr = Qp + (size_t)(b * 2048 + tq) * 512 + h * 64 + hi * 8;
  const bf16x8 qf0 = ld_bf8(qptr);
  const bf16x8 qf1 = ld_bf8(qptr + 16);
  const bf16x8 qf2 = ld_bf8(qptr + 32);
  const bf16x8 qf3 = ld_bf8(qptr + 48);

  const f32x16 z16 = {0.f, 0.f, 0.f, 0.f, 0.f, 0.f, 0.f, 0.f,
                      0.f, 0.f, 0.f, 0.f, 0.f, 0.f, 0.f, 0.f};
  f32x16 o_lo = z16, o_hi = z16;
  float m_run = -1e30f, l_run = 0.f;
  int buf = 0;

  for (int t = 0; t < 32; ++t) {
    const int s0 = t * 64;
    if (t != 31) stage(buf ^ 1, s0 + 64);

    const unsigned short* kb = &K_lds[buf][0];
    const int rswz = q31 & 7;
    f32x16 sa, sb;
    sa = mfma32(ld_bf8(kb + q31 * 64 + (((0 + hi) ^ rswz) << 3)), qf0, z16);
    sb = mfma32(ld_bf8(kb + (32 + q31) * 64 + (((0 + hi) ^ rswz) << 3)), qf0, z16);
    sa = mfma32(ld_bf8(kb + q31 * 64 + (((2 + hi) ^ rswz) << 3)), qf1, sa);
    sb = mfma32(ld_bf8(kb + (32 + q31) * 64 + (((2 + hi) ^ rswz) << 3)), qf1, sb);
    sa = mfma32(ld_bf8(kb + q31 * 64 + (((4 + hi) ^ rswz) << 3)), qf2, sa);
    sb = mfma32(ld_bf8(kb + (32 + q31) * 64 + (((4 + hi) ^ rswz) << 3)), qf2, sb);
    sa = mfma32(ld_bf8(kb + q31 * 64 + (((6 + hi) ^ rswz) << 3)), qf3, sa);
    sb = mfma32(ld_bf8(kb + (32 + q31) * 64 + (((6 + hi) ^ rswz) << 3)), qf3, sb);

    const unsigned short* vb = &V_lds[buf][0];
    bf16x8 vl[4], vh[4];
#pragma unroll
    for (int ks = 0; ks < 4; ks++) {
      vl[ks] = ld_bf8(vb + q31 * 64 + (((ks * 2 + hi) ^ rswz) << 3));
      vh[ks] = ld_bf8(vb + (32 + q31) * 64 + (((ks * 2 + hi) ^ rswz) << 3));
    }

    const int relmin = q0w - s0 - 63;
    const int relmax = q0w + 31 - s0;
    if (relmin >= 128 || relmax <= -128) {
      const float bc = (relmin >= 128) ? bias_hi : bias_lo;
#pragma unroll
      for (int r = 0; r < 16; r++) {
        sa[r] = fmaf(sa[r], SCL, bc);
        sb[r] = fmaf(sb[r], SCL, bc);
      }
    } else {
#pragma unroll
      for (int r = 0; r < 16; r++) {
        const int rowA = (r & 3) + 8 * (r >> 2) + 4 * hi;
        const int rA = tq - s0 - rowA;
        const int rB = rA - 32;
        const int iA = (rA < -128 ? -128 : (rA > 128 ? 128 : rA)) + 128;
        const int iB = (rB < -128 ? -128 : (rB > 128 ? 128 : rB)) + 128;
        sa[r] = fmaf(sa[r], SCL, bias_s[iA]);
        sb[r] = fmaf(sb[r], SCL, bias_s[iB]);
      }
    }

    const float t0 = fmaxf(fmaxf(sa[0], sa[1]), sa[2]);
    const float t1 = fmaxf(fmaxf(sa[3], sa[4]), sa[5]);
    const float t2 = fmaxf(fmaxf(sa[6], sa[7]), sa[8]);
    const float t3 = fmaxf(fmaxf(sa[9], sa[10]), sa[11]);
    const float t4 = fmaxf(fmaxf(sa[12], sa[13]), sa[14]);
    const float t5 = fmaxf(fmaxf(sa[15], sb[0]), sb[1]);
    const float t6 = fmaxf(fmaxf(sb[2], sb[3]), sb[4]);
    const float t7 = fmaxf(fmaxf(sb[5], sb[6]), sb[7]);
    const float t8 = fmaxf(fmaxf(sb[8], sb[9]), sb[10]);
    const float t9 = fmaxf(fmaxf(sb[11], sb[12]), sb[13]);
    const float ta = fmaxf(sb[14], sb[15]);
    const float u0 = fmaxf(fmaxf(t0, t1), t2);
    const float u1 = fmaxf(fmaxf(t3, t4), t5);
    const float u2 = fmaxf(fmaxf(t6, t7), t8);
    float mx = fmaxf(fmaxf(fmaxf(u0, u1), u2), fmaxf(t9, ta));
    mx = fmaxf(mx, __shfl_xor(mx, 32, 64));

    if (!__all(mx <= m_run + 8.f)) {
      const float m_new = fmaxf(m_run, mx);
      const float rsq = exp2f(m_run - m_new);
      l_run *= rsq;
      m_run = m_new;
#pragma unroll
      for (int r2 = 0; r2 < 16; r2++) {
        const int ro = (r2 & 3) + 8 * (r2 >> 2) + 4 * hi;
        const float rr = __shfl(rsq, ro, 64);
        o_lo[r2] *= rr;
        o_hi[r2] *= rr;
      }
    }

#pragma unroll
    for (int r = 0; r < 16; r++) {
      sa[r] = exp2f(sa[r] - m_run);
      sb[r] = exp2f(sb[r] - m_run);
    }
    float s8[8];
#pragma unroll
    for (int i = 0; i < 8; i++)
      s8[i] = (sa[i] + sa[i + 8]) + (sb[i] + sb[i + 8]);
    float ps = ((s8[0] + s8[1]) + (s8[2] + s8[3])) + ((s8[4] + s8[5]) + (s8[6] + s8[7]));
    ps += __shfl_xor(ps, 32, 64);
    l_run += ps;

    bf16x8 pa[4];
#pragma unroll
    for (int ks = 0; ks < 4; ks++) {
      const int c8 = (ks & 1) * 8;
      const f32x16& src = (ks < 2) ? sa : sb;
      unsigned int a0 = cvt_pk_bf16(src[c8 + 0], src[c8 + 1]);
      unsigned int b0 = cvt_pk_bf16(src[c8 + 4], src[c8 + 5]);
      unsigned int a1 = cvt_pk_bf16(src[c8 + 2], src[c8 + 3]);
      unsigned int b1 = cvt_pk_bf16(src[c8 + 6], src[c8 + 7]);
      plane32_swap(a0, b0);
      plane32_swap(a1, b1);
      pa[ks] = __builtin_bit_cast(bf16x8, u32x4{a0, a1, b0, b1});
    }

#pragma unroll
    for (int ks = 0; ks < 4; ks++) {
      o_lo = mfma32(pa[ks], vl[ks], o_lo);
      o_hi = mfma32(pa[ks], vh[ks], o_hi);
    }

    __syncthreads();
    buf ^= 1;
  }

  const float inv = 1.f / l_run;
#pragma unroll
  for (int r2 = 0; r2 < 16; r2++) {
    const int ro = (r2 & 3) + 8 * (r2 >> 2) + 4 * hi;
    const float rr = __shfl(inv, ro, 64);
    unsigned short* op = At + (size_t)(b * 2048 + q0w + ro) * 512 + h * 64;
    op[q31] = f2bf(o_lo[r2] * rr);
    op[32 + q31] = f2bf(o_hi[r2] * rr);
  }
}

// ---------------- host ----------------
extern "C" void kernel_launch(void* const* d_in, const int* in_sizes, int n_in,
                              void* d_out, int out_size, void* d_ws, size_t ws_size,
                              hipStream_t stream) {
  const float* query = (const float*)d_in[0];
  const float* key   = (const float*)d_in[1];
  const float* value = (const float*)d_in[2];
  const float* Wq = (const float*)d_in[3];
  const float* bq = (const float*)d_in[4];
  const float* Wk = (const float*)d_in[5];
  const float* bk = (const float*)d_in[6];
  const float* Wv = (const float*)d_in[7];
  const float* bv = (const float*)d_in[8];
  const float* Wo = (const float*)d_in[9];
  const float* bo = (const float*)d_in[10];
  const float* rel = (const float*)d_in[11];

  char* ws = (char*)d_ws;
  const size_t SZX = (size_t)4 * 2048 * 512;
  const size_t SZW = (size_t)512 * 512;
  unsigned short* xq = (unsigned short*)ws;
  unsigned short* xk = xq + SZX;
  unsigned short* xv = xk + SZX;
  unsigned short* wq = xv + SZX;
  unsigned short* wk = wq + SZW;
  unsigned short* wv = wk + SZW;
  unsigned short* wo = wv + SZW;
  unsigned short* Qp = wo + SZW;
  unsigned short* Kp = Qp + SZX;
  unsigned short* Vt = Kp + SZX;
  unsigned short* At = Vt + SZX;

  cvt_all<<<dim3(13312), dim3(256), 0, stream>>>(query, key, value, Wq, Wk, Wv, Wo, xq);

  dim3 gg(4, 64), blk(256);
  gemm_bt<0><<<gg, blk, 0, stream>>>(xq, wq, bq, (void*)Qp);
  gemm_bt<0><<<gg, blk, 0, stream>>>(xk, wk, bk, (void*)Kp);
  gemm_bt<1><<<gg, blk, 0, stream>>>(xv, wv, bv, (void*)Vt);

  attn_kernel<<<dim3(512), blk, 0, stream>>>(Qp, Kp, Vt, rel, At);

  gemm_bt<2><<<gg, blk, 0, stream>>>(At, wo, bo, d_out);
}

// Round 12
// 113.960 us; speedup vs baseline: 2.0604x; 1.2152x over previous
//
#include <hip/hip_runtime.h>

typedef __attribute__((ext_vector_type(4))) float f32x4;
typedef __attribute__((ext_vector_type(16))) float f32x16;
typedef __attribute__((ext_vector_type(4))) unsigned short u16x4;
typedef __attribute__((ext_vector_type(8))) unsigned short u16x8;
typedef __attribute__((ext_vector_type(4))) unsigned int u32x4;
typedef __attribute__((ext_vector_type(8))) __bf16 bf16x8;

#define SZX_E ((size_t)4 * 2048 * 512)  // elements per activation tensor
#define SZW_E ((size_t)512 * 512)

__device__ __forceinline__ unsigned short f2bf(float f) {
  unsigned int u = __builtin_bit_cast(unsigned int, f);
  u += 0x7fffu + ((u >> 16) & 1u);
  return (unsigned short)(u >> 16);
}

__device__ __forceinline__ bf16x8 ld_bf8(const unsigned short* p) {
  return __builtin_bit_cast(bf16x8, *(const u16x8*)p);
}

__device__ __forceinline__ f32x4 mfma16(bf16x8 a, bf16x8 b, f32x4 c) {
  return __builtin_amdgcn_mfma_f32_16x16x32_bf16(a, b, c, 0, 0, 0);
}

__device__ __forceinline__ f32x16 mfma32(bf16x8 a, bf16x8 b, f32x16 c) {
  return __builtin_amdgcn_mfma_f32_32x32x16_bf16(a, b, c, 0, 0, 0);
}

__device__ __forceinline__ unsigned int cvt_pk_bf16(float lo, float hi) {
  unsigned int r;
  asm("v_cvt_pk_bf16_f32 %0, %1, %2" : "=v"(r) : "v"(lo), "v"(hi));
  return r;
}

__device__ __forceinline__ void plane32_swap(unsigned int& a, unsigned int& b) {
  asm("v_permlane32_swap_b32 %0, %1" : "+v"(a), "+v"(b));
}

// raw v_exp_f32 (2^x). Valid here: args <= 0, results >= 2^-40 (normal range),
// so identical to exp2f without OCML's range-guard overhead (~5 inst -> 1).
__device__ __forceinline__ float exp2_fast(float x) {
  float r;
  asm("v_exp_f32 %0, %1" : "=v"(r) : "v"(x));
  return r;
}

// async global->LDS, 16B per lane; LDS dest = WAVE-UNIFORM base, HW adds lane*16
__device__ __forceinline__ void gload16(const void* g, void* l) {
  __builtin_amdgcn_global_load_lds(
      (const __attribute__((address_space(1))) unsigned int*)g,
      (__attribute__((address_space(3))) unsigned int*)l, 16, 0, 0);
}

// ---------------- fused fp32 -> bf16 convert (all 7 tensors, one launch) ----------------
__global__ __launch_bounds__(256) void cvt_all(const float* __restrict__ q_,
                                               const float* __restrict__ k_,
                                               const float* __restrict__ v_,
                                               const float* __restrict__ wq_,
                                               const float* __restrict__ wk_,
                                               const float* __restrict__ wv_,
                                               const float* __restrict__ wo_,
                                               unsigned short* __restrict__ out) {
  const int bq = blockIdx.x;
  const float* src;
  size_t segbase, li;
  if (bq < 12288) {
    const int s = bq >> 12;
    src = (s == 0) ? q_ : (s == 1) ? k_ : v_;
    li = (size_t)(bq & 4095) * 256 + threadIdx.x;
    segbase = (size_t)s * 4194304;
  } else {
    const int s = (bq - 12288) >> 8;
    src = (s == 0) ? wq_ : (s == 1) ? wk_ : (s == 2) ? wv_ : wo_;
    li = (size_t)((bq - 12288) & 255) * 256 + threadIdx.x;
    segbase = 12582912 + (size_t)s * 262144;
  }
  const f32x4 v = *(const f32x4*)(src + li * 4);
  u16x4 r;
  r[0] = f2bf(v[0]); r[1] = f2bf(v[1]); r[2] = f2bf(v[2]); r[3] = f2bf(v[3]);
  *(u16x4*)(out + segbase + li * 4) = r;
}

// ---------------- fused QKV GEMM: z = 0/1/2 -> Q/K/V projection ----------------
// base = bf16 ws: [xq xk xv][wq wk wv wo][Qp Kp Vt ...]. 768 blocks = 3/CU co-resident.
__global__ __launch_bounds__(256) void gemm_qkv(const unsigned short* __restrict__ base,
                                                const float* __restrict__ bq,
                                                const float* __restrict__ bk,
                                                const float* __restrict__ bv,
                                                unsigned short* __restrict__ outb) {
  __shared__ unsigned short Asb[2][4096];
  __shared__ unsigned short Bsb[2][4096];
  const int z = blockIdx.z;
  const unsigned short* A = base + (size_t)z * SZX_E;
  const unsigned short* Bw = base + 3 * SZX_E + (size_t)z * SZW_E;
  const float* bias = (z == 0) ? bq : (z == 1) ? bk : bv;

  const int tid = threadIdx.x;
  const int l = tid & 63;
  const int w = tid >> 6;
  const int g = l >> 4;
  const int lr = l & 15;
  const int mB = blockIdx.y * 128;
  const int nB = blockIdx.x * 128;
  const int m0 = (w >> 1) * 64;
  const int n0 = (w & 1) * 64;
  const int ubase = tid & ~63;

  auto stage = [&](int bufi, int kk) {
#pragma unroll
    for (int i = 0; i < 2; i++) {
      const int idx = i * 256 + tid;
      const int ub = i * 256 + ubase;
      const int r = idx >> 2, c = idx & 3;
      gload16((const char*)A + ((size_t)(mB + r) * 512 + kk + c * 8) * 2,
              (char*)&Asb[bufi][0] + ub * 16);
      gload16((const char*)Bw + ((size_t)(nB + r) * 512 + kk + c * 8) * 2,
              (char*)&Bsb[bufi][0] + ub * 16);
    }
  };

  f32x4 acc[4][4];
#pragma unroll
  for (int i = 0; i < 4; i++)
#pragma unroll
    for (int j = 0; j < 4; j++) acc[i][j] = f32x4{0.f, 0.f, 0.f, 0.f};

  stage(0, 0);
  __syncthreads();
  int buf = 0;

  for (int ks = 0; ks < 16; ++ks) {
    if (ks < 15) stage(buf ^ 1, (ks + 1) * 32);
    bf16x8 af[4], bfr[4];
#pragma unroll
    for (int t = 0; t < 4; t++) {
      af[t] = ld_bf8(&Asb[buf][(m0 + t * 16 + lr) * 32 + g * 8]);
      bfr[t] = ld_bf8(&Bsb[buf][(n0 + t * 16 + lr) * 32 + g * 8]);
    }
#pragma unroll
    for (int i = 0; i < 4; i++)
#pragma unroll
      for (int j = 0; j < 4; j++)
        acc[i][j] = mfma16(af[i], bfr[j], acc[i][j]);
    __syncthreads();
    buf ^= 1;
  }

  unsigned short* outz = outb + (size_t)z * SZX_E;  // Qp / Kp / Vt
#pragma unroll
  for (int j = 0; j < 4; j++) {
    const int n = nB + n0 + j * 16 + lr;
    const float bn = bias[n];
#pragma unroll
    for (int i = 0; i < 4; i++) {
#pragma unroll
      for (int r = 0; r < 4; r++) {
        const int m = mB + m0 + i * 16 + g * 4 + r;
        const float v = acc[i][j][r] + bn;
        if (z < 2) {
          outz[(size_t)m * 512 + n] = f2bf(v);
        } else {
          const int bb = m >> 11, s = m & 2047;
          const int hh = n >> 6, d = n & 63;
          outz[((size_t)((bb * 8 + hh) * 64 + d) << 11) + s] = f2bf(v);
        }
      }
    }
  }
}

// ---------------- output GEMM: fp32 out + bias ----------------
__global__ __launch_bounds__(256) void gemm_o(const unsigned short* __restrict__ A,
                                              const unsigned short* __restrict__ Bw,
                                              const float* __restrict__ bias,
                                              float* __restrict__ Cout) {
  __shared__ unsigned short Asb[2][4096];
  __shared__ unsigned short Bsb[2][4096];
  const int tid = threadIdx.x;
  const int l = tid & 63;
  const int w = tid >> 6;
  const int g = l >> 4;
  const int lr = l & 15;
  const int mB = blockIdx.y * 128;
  const int nB = blockIdx.x * 128;
  const int m0 = (w >> 1) * 64;
  const int n0 = (w & 1) * 64;
  const int ubase = tid & ~63;

  auto stage = [&](int bufi, int kk) {
#pragma unroll
    for (int i = 0; i < 2; i++) {
      const int idx = i * 256 + tid;
      const int ub = i * 256 + ubase;
      const int r = idx >> 2, c = idx & 3;
      gload16((const char*)A + ((size_t)(mB + r) * 512 + kk + c * 8) * 2,
              (char*)&Asb[bufi][0] + ub * 16);
      gload16((const char*)Bw + ((size_t)(nB + r) * 512 + kk + c * 8) * 2,
              (char*)&Bsb[bufi][0] + ub * 16);
    }
  };

  f32x4 acc[4][4];
#pragma unroll
  for (int i = 0; i < 4; i++)
#pragma unroll
    for (int j = 0; j < 4; j++) acc[i][j] = f32x4{0.f, 0.f, 0.f, 0.f};

  stage(0, 0);
  __syncthreads();
  int buf = 0;

  for (int ks = 0; ks < 16; ++ks) {
    if (ks < 15) stage(buf ^ 1, (ks + 1) * 32);
    bf16x8 af[4], bfr[4];
#pragma unroll
    for (int t = 0; t < 4; t++) {
      af[t] = ld_bf8(&Asb[buf][(m0 + t * 16 + lr) * 32 + g * 8]);
      bfr[t] = ld_bf8(&Bsb[buf][(n0 + t * 16 + lr) * 32 + g * 8]);
    }
#pragma unroll
    for (int i = 0; i < 4; i++)
#pragma unroll
      for (int j = 0; j < 4; j++)
        acc[i][j] = mfma16(af[i], bfr[j], acc[i][j]);
    __syncthreads();
    buf ^= 1;
  }

#pragma unroll
  for (int j = 0; j < 4; j++) {
    const int n = nB + n0 + j * 16 + lr;
    const float bn = bias[n];
#pragma unroll
    for (int i = 0; i < 4; i++) {
#pragma unroll
      for (int r = 0; r < 4; r++) {
        const int m = mB + m0 + i * 16 + g * 4 + r;
        Cout[(size_t)m * 512 + n] = acc[i][j][r] + bn;
      }
    }
  }
}

// ---------------- flash attention: LDS-staged K/V, 4 waves x 32 q-rows ----------------
// (r10 structure, verified; exp2f -> raw v_exp_f32)
__global__ __launch_bounds__(256, 2) void attn_kernel(const unsigned short* __restrict__ Qp,
                                                      const unsigned short* __restrict__ Kp,
                                                      const unsigned short* __restrict__ Vt,
                                                      const float* __restrict__ rel_emb,
                                                      unsigned short* __restrict__ At) {
  __shared__ float bias_s[257];
  __shared__ unsigned short K_lds[2][4096];
  __shared__ unsigned short V_lds[2][4096];
  const int bid = blockIdx.x;
  const int qb = bid & 15;
  const int h = (bid >> 4) & 7;
  const int b = bid >> 7;
  const int tid = threadIdx.x;
  const int lane = tid & 63, w = tid >> 6;
  const int hi = lane >> 5, q31 = lane & 31;
  const int q0w = qb * 128 + w * 32;
  const int tq = q0w + q31;
  const float SCL = 0.125f * 1.44269504f;

  const char* kstage = (const char*)Kp + ((size_t)b * 2048 * 512 + h * 64) * 2;
  const char* vstage = (const char*)Vt + ((size_t)(b * 8 + h) * 64 * 2048) * 2;

  auto stage = [&](int bufi, int s0n) {
#pragma unroll
    for (int ii = 0; ii < 4; ii++) {
      const int ins = (w & 1) * 4 + ii;
      const int r = ins * 8 + (lane >> 3);
      const int ch = (lane & 7) ^ (r & 7);
      if (w < 2) {
        gload16(kstage + (size_t)(s0n + r) * 1024 + ch * 16,
                (char*)&K_lds[bufi][0] + ins * 1024);
      } else {
        gload16(vstage + (size_t)r * 4096 + (size_t)s0n * 2 + ch * 16,
                (char*)&V_lds[bufi][0] + ins * 1024);
      }
    }
  };

  for (int i = tid; i < 257; i += 256) bias_s[i] = rel_emb[i * 8 + h] * 1.44269504f;
  stage(0, 0);
  __syncthreads();
  const float bias_lo = bias_s[0], bias_hi = bias_s[256];

  const unsigned short* qptr = Qp + (size_t)(b * 2048 + tq) * 512 + h * 64 + hi * 8;
  const bf16x8 qf0 = ld_bf8(qptr);
  const bf16x8 qf1 = ld_bf8(qptr + 16);
  const bf16x8 qf2 = ld_bf8(qptr + 32);
  const bf16x8 qf3 = ld_bf8(qptr + 48);

  const f32x16 z16 = {0.f, 0.f, 0.f, 0.f, 0.f, 0.f, 0.f, 0.f,
                      0.f, 0.f, 0.f, 0.f, 0.f, 0.f, 0.f, 0.f};
  f32x16 o_lo = z16, o_hi = z16;
  float m_run = -1e30f, l_run = 0.f;
  int buf = 0;

  for (int t = 0; t < 32; ++t) {
    const int s0 = t * 64;
    if (t != 31) stage(buf ^ 1, s0 + 64);

    const unsigned short* kb = &K_lds[buf][0];
    const int rswz = q31 & 7;
    f32x16 sa, sb;
    sa = mfma32(ld_bf8(kb + q31 * 64 + (((0 + hi) ^ rswz) << 3)), qf0, z16);
    sb = mfma32(ld_bf8(kb + (32 + q31) * 64 + (((0 + hi) ^ rswz) << 3)), qf0, z16);
    sa = mfma32(ld_bf8(kb + q31 * 64 + (((2 + hi) ^ rswz) << 3)), qf1, sa);
    sb = mfma32(ld_bf8(kb + (32 + q31) * 64 + (((2 + hi) ^ rswz) << 3)), qf1, sb);
    sa = mfma32(ld_bf8(kb + q31 * 64 + (((4 + hi) ^ rswz) << 3)), qf2, sa);
    sb = mfma32(ld_bf8(kb + (32 + q31) * 64 + (((4 + hi) ^ rswz) << 3)), qf2, sb);
    sa = mfma32(ld_bf8(kb + q31 * 64 + (((6 + hi) ^ rswz) << 3)), qf3, sa);
    sb = mfma32(ld_bf8(kb + (32 + q31) * 64 + (((6 + hi) ^ rswz) << 3)), qf3, sb);

    const unsigned short* vb = &V_lds[buf][0];
    bf16x8 vl[4], vh[4];
#pragma unroll
    for (int ks = 0; ks < 4; ks++) {
      vl[ks] = ld_bf8(vb + q31 * 64 + (((ks * 2 + hi) ^ rswz) << 3));
      vh[ks] = ld_bf8(vb + (32 + q31) * 64 + (((ks * 2 + hi) ^ rswz) << 3));
    }

    const int relmin = q0w - s0 - 63;
    const int relmax = q0w + 31 - s0;
    if (relmin >= 128 || relmax <= -128) {
      const float bc = (relmin >= 128) ? bias_hi : bias_lo;
#pragma unroll
      for (int r = 0; r < 16; r++) {
        sa[r] = fmaf(sa[r], SCL, bc);
        sb[r] = fmaf(sb[r], SCL, bc);
      }
    } else {
#pragma unroll
      for (int r = 0; r < 16; r++) {
        const int rowA = (r & 3) + 8 * (r >> 2) + 4 * hi;
        const int rA = tq - s0 - rowA;
        const int rB = rA - 32;
        const int iA = (rA < -128 ? -128 : (rA > 128 ? 128 : rA)) + 128;
        const int iB = (rB < -128 ? -128 : (rB > 128 ? 128 : rB)) + 128;
        sa[r] = fmaf(sa[r], SCL, bias_s[iA]);
        sb[r] = fmaf(sb[r], SCL, bias_s[iB]);
      }
    }

    const float t0 = fmaxf(fmaxf(sa[0], sa[1]), sa[2]);
    const float t1 = fmaxf(fmaxf(sa[3], sa[4]), sa[5]);
    const float t2 = fmaxf(fmaxf(sa[6], sa[7]), sa[8]);
    const float t3 = fmaxf(fmaxf(sa[9], sa[10]), sa[11]);
    const float t4 = fmaxf(fmaxf(sa[12], sa[13]), sa[14]);
    const float t5 = fmaxf(fmaxf(sa[15], sb[0]), sb[1]);
    const float t6 = fmaxf(fmaxf(sb[2], sb[3]), sb[4]);
    const float t7 = fmaxf(fmaxf(sb[5], sb[6]), sb[7]);
    const float t8 = fmaxf(fmaxf(sb[8], sb[9]), sb[10]);
    const float t9 = fmaxf(fmaxf(sb[11], sb[12]), sb[13]);
    const float ta = fmaxf(sb[14], sb[15]);
    const float u0 = fmaxf(fmaxf(t0, t1), t2);
    const float u1 = fmaxf(fmaxf(t3, t4), t5);
    const float u2 = fmaxf(fmaxf(t6, t7), t8);
    float mx = fmaxf(fmaxf(fmaxf(u0, u1), u2), fmaxf(t9, ta));
    mx = fmaxf(mx, __shfl_xor(mx, 32, 64));

    if (!__all(mx <= m_run + 8.f)) {
      const float m_new = fmaxf(m_run, mx);
      const float rsq = exp2_fast(m_run - m_new);
      l_run *= rsq;
      m_run = m_new;
#pragma unroll
      for (int r2 = 0; r2 < 16; r2++) {
        const int ro = (r2 & 3) + 8 * (r2 >> 2) + 4 * hi;
        const float rr = __shfl(rsq, ro, 64);
        o_lo[r2] *= rr;
        o_hi[r2] *= rr;
      }
    }

#pragma unroll
    for (int r = 0; r < 16; r++) {
      sa[r] = exp2_fast(sa[r] - m_run);
      sb[r] = exp2_fast(sb[r] - m_run);
    }
    float s8[8];
#pragma unroll
    for (int i = 0; i < 8; i++)
      s8[i] = (sa[i] + sa[i + 8]) + (sb[i] + sb[i + 8]);
    float ps = ((s8[0] + s8[1]) + (s8[2] + s8[3])) + ((s8[4] + s8[5]) + (s8[6] + s8[7]));
    ps += __shfl_xor(ps, 32, 64);
    l_run += ps;

    bf16x8 pa[4];
#pragma unroll
    for (int ks = 0; ks < 4; ks++) {
      const int c8 = (ks & 1) * 8;
      const f32x16& src = (ks < 2) ? sa : sb;
      unsigned int a0 = cvt_pk_bf16(src[c8 + 0], src[c8 + 1]);
      unsigned int b0 = cvt_pk_bf16(src[c8 + 4], src[c8 + 5]);
      unsigned int a1 = cvt_pk_bf16(src[c8 + 2], src[c8 + 3]);
      unsigned int b1 = cvt_pk_bf16(src[c8 + 6], src[c8 + 7]);
      plane32_swap(a0, b0);
      plane32_swap(a1, b1);
      pa[ks] = __builtin_bit_cast(bf16x8, u32x4{a0, a1, b0, b1});
    }

#pragma unroll
    for (int ks = 0; ks < 4; ks++) {
      o_lo = mfma32(pa[ks], vl[ks], o_lo);
      o_hi = mfma32(pa[ks], vh[ks], o_hi);
    }

    __syncthreads();
    buf ^= 1;
  }

  const float inv = 1.f / l_run;
#pragma unroll
  for (int r2 = 0; r2 < 16; r2++) {
    const int ro = (r2 & 3) + 8 * (r2 >> 2) + 4 * hi;
    const float rr = __shfl(inv, ro, 64);
    unsigned short* op = At + (size_t)(b * 2048 + q0w + ro) * 512 + h * 64;
    op[q31] = f2bf(o_lo[r2] * rr);
    op[32 + q31] = f2bf(o_hi[r2] * rr);
  }
}

// ---------------- host ----------------
extern "C" void kernel_launch(void* const* d_in, const int* in_sizes, int n_in,
                              void* d_out, int out_size, void* d_ws, size_t ws_size,
                              hipStream_t stream) {
  const float* query = (const float*)d_in[0];
  const float* key   = (const float*)d_in[1];
  const float* value = (const float*)d_in[2];
  const float* Wq = (const float*)d_in[3];
  const float* bq = (const float*)d_in[4];
  const float* Wk = (const float*)d_in[5];
  const float* bk = (const float*)d_in[6];
  const float* Wv = (const float*)d_in[7];
  const float* bv = (const float*)d_in[8];
  const float* Wo = (const float*)d_in[9];
  const float* bo = (const float*)d_in[10];
  const float* rel = (const float*)d_in[11];

  char* ws = (char*)d_ws;
  unsigned short* base = (unsigned short*)ws;       // xq xk xv | wq wk wv wo | ...
  unsigned short* wo = base + 3 * SZX_E + 3 * SZW_E;
  unsigned short* Qp = base + 3 * SZX_E + 4 * SZW_E;
  unsigned short* Kp = Qp + SZX_E;
  unsigned short* Vt = Kp + SZX_E;
  unsigned short* At = Vt + SZX_E;

  cvt_all<<<dim3(13312), dim3(256), 0, stream>>>(query, key, value, Wq, Wk, Wv, Wo, base);

  dim3 blk(256);
  gemm_qkv<<<dim3(4, 64, 3), blk, 0, stream>>>(base, bq, bk, bv, Qp);

  attn_kernel<<<dim3(512), blk, 0, stream>>>(Qp, Kp, Vt, rel, At);

  gemm_o<<<dim3(4, 64), blk, 0, stream>>>(At, wo, bo, (float*)d_out);
}